// Round 1
// baseline (2769.296 us; speedup 1.0000x reference)
//
#include <hip/hip_runtime.h>
#include <cstdint>
#include <cstddef>

// Problem constants
#define B_  512
#define L_  60
#define D_  300
#define H_  256
#define BT  1024          // combined batch (2 branches)
#define KX  320           // D padded to multiple of 32 (300 -> 320, zeros in pad)
#define KL  576           // LSTM GEMM K: 320 (x) + 256 (h)
#define NG  1024          // 4*H gate width

typedef _Float16 half8  __attribute__((ext_vector_type(8)));
typedef _Float16 half4_t __attribute__((ext_vector_type(4)));
typedef float    floatx4 __attribute__((ext_vector_type(4)));

__device__ __forceinline__ float fast_tanh(float x){ float e = __expf(2.f*x); return 1.f - 2.f/(e + 1.f); }
__device__ __forceinline__ float sigm(float x){ return 1.f/(1.f + __expf(-x)); }

#define MFMA16(a,b,c) __builtin_amdgcn_mfma_f32_16x16x32_f16(a,b,c,0,0,0)

// ---------------------------------------------------------------- utility
__global__ void k_zero(uint32_t* __restrict__ p, int n){
    int i = blockIdx.x*blockDim.x + threadIdx.x;
    int st = gridDim.x*blockDim.x;
    for (; i < n; i += st) p[i] = 0u;
}

// Gather embeddings for [input1; input2] -> X16[1024][60][320] f16 (pad zeros)
// grid: 1024*60*40/256 = 9600 blocks, each thread one 8-elem chunk
__global__ __launch_bounds__(256) void k_gather(const float* __restrict__ E,
    const int* __restrict__ in1, const int* __restrict__ in2, _Float16* __restrict__ X16)
{
    int gid = blockIdx.x*256 + threadIdx.x;
    int row = gid / (L_*40);
    int rem = gid - row*(L_*40);
    int t  = rem / 40;
    int ch = rem - t*40;
    int k0 = ch*8;
    int tok = (row < B_) ? in1[row*L_ + t] : in2[(row - B_)*L_ + t];
    const float* src = E + (size_t)tok*D_ + k0;
    half8 out;
    #pragma unroll
    for (int k = 0; k < 8; ++k) out[k] = (_Float16)0.f;
    if (k0 + 8 <= D_) {
        float4 a = *(const float4*)(src);
        float4 b = *(const float4*)(src + 4);
        out[0]=(_Float16)a.x; out[1]=(_Float16)a.y; out[2]=(_Float16)a.z; out[3]=(_Float16)a.w;
        out[4]=(_Float16)b.x; out[5]=(_Float16)b.y; out[6]=(_Float16)b.z; out[7]=(_Float16)b.w;
    } else if (k0 < D_) {  // k0 == 296: 4 real + 4 pad
        float4 a = *(const float4*)(src);
        out[0]=(_Float16)a.x; out[1]=(_Float16)a.y; out[2]=(_Float16)a.z; out[3]=(_Float16)a.w;
    }
    *(half8*)(X16 + ((size_t)row*L_ + t)*KX + k0) = out;
}

// LSTM weights -> BcatT[set][n=1024][k=576] f16; k<300 Wx, 300..319 zero, >=320 Wh
// grid: 2*576*1024/256 = 4608 blocks
__global__ __launch_bounds__(256) void k_prep_lstmW(const float* __restrict__ Wx1, const float* __restrict__ Wh1,
    const float* __restrict__ Wx2, const float* __restrict__ Wh2, _Float16* __restrict__ BcatT)
{
    int idx = blockIdx.x*256 + threadIdx.x;
    int set = (idx >= KL*NG) ? 1 : 0;
    int rem = idx - set*(KL*NG);
    int k = rem >> 10, n = rem & 1023;
    const float* Wx = set ? Wx2 : Wx1;
    const float* Wh = set ? Wh2 : Wh1;
    float v = 0.f;
    if (k < D_)       v = Wx[k*NG + n];
    else if (k >= KX) v = Wh[(k - KX)*NG + n];
    BcatT[((size_t)set*NG + n)*KL + k] = (_Float16)v;
}

// Attention weights transposed to [n][k] f16.
// AW layout (elem offsets): WyT@0 [256][256], BattnT@65536 [256][512] (Wh_a|Wr_a),
// WtT@196608 [256][256], WfinT@262144 [256][512] (Wp_a|Wxa). grid 1536 blocks.
__global__ __launch_bounds__(256) void k_prep_attnW(const float* __restrict__ W_y,
    const float* __restrict__ Wh_a, const float* __restrict__ Wr_a, const float* __restrict__ Wt_a,
    const float* __restrict__ Wp_a, const float* __restrict__ Wxa, _Float16* __restrict__ AW)
{
    int idx = blockIdx.x*256 + threadIdx.x;
    float v; int dst;
    if (idx < 65536) {
        int k = idx >> 8, n = idx & 255;
        v = W_y[idx];
        dst = n*256 + k;
    } else if (idx < 196608) {
        int j = idx - 65536; int k = j >> 8, n = j & 255;
        v = (k < 256) ? Wh_a[k*256 + n] : Wr_a[(k - 256)*256 + n];
        dst = 65536 + n*512 + k;
    } else if (idx < 262144) {
        int j = idx - 196608; int k = j >> 8, n = j & 255;
        v = Wt_a[j];
        dst = 196608 + n*256 + k;
    } else {
        int j = idx - 262144; int k = j >> 8, n = j & 255;
        v = (k < 256) ? Wp_a[k*256 + n] : Wxa[(k - 256)*256 + n];
        dst = 262144 + n*512 + k;
    }
    AW[dst] = (_Float16)v;
}

// ---------------------------------------------------------------- fused LSTM step
// grid (ht=16, mt=16, set=2), 256 thr. gates GEMM [64 rows]x[4 gates x 16 h] K=576,
// then cell update + Y write + h ping-pong, all in one kernel.
__global__ __launch_bounds__(256) void k_lstm_step(
    const _Float16* __restrict__ X16, _Float16* __restrict__ h16,
    float* __restrict__ c, _Float16* __restrict__ Y16,
    const _Float16* __restrict__ BcatT,
    const float* __restrict__ b1, const float* __restrict__ b2,
    const int* __restrict__ s1, const int* __restrict__ s2, int t)
{
    __shared__ _Float16 sA[64*40];
    __shared__ _Float16 sB[64*40];
    __shared__ float    sG[64*65];
    const int tid = threadIdx.x;
    const int ht = blockIdx.x, mt = blockIdx.y, set = blockIdx.z;
    const int m0 = mt*64;
    const int lane = tid & 63, wv = tid >> 6;
    const int wm = (wv & 1)*32, wn = (wv >> 1)*32;
    const int q = lane >> 4, lm = lane & 15;
    const int p_in = t & 1, p_out = (t + 1) & 1;
    const _Float16* hin  = h16 + ((size_t)(set*2 + p_in))*BT*H_;
    _Float16*       hout = h16 + ((size_t)(set*2 + p_out))*BT*H_;

    const int am = tid >> 2;           // staging row 0..63
    const int kg = (tid & 3)*8;        // staging k offset
    const int grow_a = m0 + am;
    const int xrow = set ? ((grow_a + 512) & 1023) : grow_a;
    const _Float16* aX = X16 + ((size_t)xrow*L_ + t)*KX;
    const _Float16* aH = hin + (size_t)grow_a*H_;
    const int gn = ((am >> 4) << 8) + ht*16 + (am & 15);   // gate-strided col
    const _Float16* bRow = BcatT + ((size_t)set*NG + gn)*KL;

    floatx4 acc00 = {0.f,0.f,0.f,0.f}, acc01 = acc00, acc10 = acc00, acc11 = acc00;

    for (int ch = 0; ch < 18; ++ch) {
        const int k0 = ch*32;
        half8 av = (k0 < KX) ? *(const half8*)(aX + k0 + kg)
                             : *(const half8*)(aH + (k0 - KX) + kg);
        half8 bv = *(const half8*)(bRow + k0 + kg);
        __syncthreads();
        *(half8*)(sA + am*40 + kg) = av;
        *(half8*)(sB + am*40 + kg) = bv;
        __syncthreads();
        half8 a0v = *(const half8*)(sA + (wm + lm)*40 + q*8);
        half8 a1v = *(const half8*)(sA + (wm + 16 + lm)*40 + q*8);
        half8 b0v = *(const half8*)(sB + (wn + lm)*40 + q*8);
        half8 b1v = *(const half8*)(sB + (wn + 16 + lm)*40 + q*8);
        acc00 = MFMA16(a0v, b0v, acc00); acc01 = MFMA16(a0v, b1v, acc01);
        acc10 = MFMA16(a1v, b0v, acc10); acc11 = MFMA16(a1v, b1v, acc11);
    }
    __syncthreads();
    {
        int rb = wm + q*4, col = wn + lm;
        #pragma unroll
        for (int r = 0; r < 4; ++r) {
            sG[(rb + r)*65 + col]           = acc00[r];
            sG[(rb + r)*65 + col + 16]      = acc01[r];
            sG[(rb + 16 + r)*65 + col]      = acc10[r];
            sG[(rb + 16 + r)*65 + col + 16] = acc11[r];
        }
    }
    __syncthreads();
    const float* bias = set ? b2 : b1;
    for (int idx = tid; idx < 1024; idx += 256) {
        int row = idx & 63, hh = idx >> 6;
        int grow = m0 + row;
        int h = ht*16 + hh;
        float gi = sG[row*65 + hh]      + bias[h];
        float gj = sG[row*65 + 16 + hh] + bias[256 + h];
        float gf = sG[row*65 + 32 + hh] + bias[512 + h];
        float go = sG[row*65 + 48 + hh] + bias[768 + h];
        int sl = (set == 0) ? ((grow < B_) ? s1[grow] : s2[grow - B_])
                            : ((grow < B_) ? s2[grow] : s1[grow - B_]);
        size_t ci = ((size_t)set*BT + grow)*H_ + h;
        float c_old = c[ci];
        float c_new = c_old*sigm(gf + 1.f) + sigm(gi)*fast_tanh(gj);
        float h_new = fast_tanh(c_new)*sigm(go);
        bool act = (t < sl);
        float h_old = (float)hin[(size_t)grow*H_ + h];
        c[ci] = act ? c_new : c_old;
        hout[(size_t)grow*H_ + h] = (_Float16)(act ? h_new : h_old);
        Y16[(((size_t)set*BT + grow)*L_ + t)*H_ + h] = act ? (_Float16)h_new : (_Float16)0.f;
    }
}

// ---------------------------------------------------------------- WyY = Y(set0) @ W_y
// grid (nt=4, mt=960): M=61440, N=256, K=256, f16 out
__global__ __launch_bounds__(256) void k_gemm_wyy(const _Float16* __restrict__ Y0,
    const _Float16* __restrict__ WyT, _Float16* __restrict__ WyY16)
{
    __shared__ _Float16 sA[64*40];
    __shared__ _Float16 sB[64*40];
    const int tid = threadIdx.x;
    const int n0 = blockIdx.x*64, m0 = blockIdx.y*64;
    const int lane = tid & 63, wv = tid >> 6;
    const int wm = (wv & 1)*32, wn = (wv >> 1)*32;
    const int q = lane >> 4, lm = lane & 15;
    const int am = tid >> 2, kg = (tid & 3)*8;
    const _Float16* aRow = Y0  + (size_t)(m0 + am)*H_;
    const _Float16* bRow = WyT + (size_t)(n0 + am)*H_;
    floatx4 acc00 = {0.f,0.f,0.f,0.f}, acc01 = acc00, acc10 = acc00, acc11 = acc00;
    for (int ch = 0; ch < 8; ++ch) {
        const int k0 = ch*32;
        half8 av = *(const half8*)(aRow + k0 + kg);
        half8 bv = *(const half8*)(bRow + k0 + kg);
        __syncthreads();
        *(half8*)(sA + am*40 + kg) = av;
        *(half8*)(sB + am*40 + kg) = bv;
        __syncthreads();
        half8 a0v = *(const half8*)(sA + (wm + lm)*40 + q*8);
        half8 a1v = *(const half8*)(sA + (wm + 16 + lm)*40 + q*8);
        half8 b0v = *(const half8*)(sB + (wn + lm)*40 + q*8);
        half8 b1v = *(const half8*)(sB + (wn + 16 + lm)*40 + q*8);
        acc00 = MFMA16(a0v, b0v, acc00); acc01 = MFMA16(a0v, b1v, acc01);
        acc10 = MFMA16(a1v, b0v, acc10); acc11 = MFMA16(a1v, b1v, acc11);
    }
    int rb = m0 + wm + q*4, col = n0 + wn + lm;
    #pragma unroll
    for (int r = 0; r < 4; ++r) {
        WyY16[(size_t)(rb + r)*H_ + col]           = (_Float16)acc00[r];
        WyY16[(size_t)(rb + r)*H_ + col + 16]      = (_Float16)acc01[r];
        WyY16[(size_t)(rb + 16 + r)*H_ + col]      = (_Float16)acc10[r];
        WyY16[(size_t)(rb + 16 + r)*H_ + col + 16] = (_Float16)acc11[r];
    }
}

// ---------------------------------------------------------------- attention per-step GEMMs
// z=0: tmp = [Y2_t | r] @ (Wh_a|Wr_a)  (K=512);  z=1: rT = r @ Wt_a (K=256)
// grid (nt=4, mt=16, z=2)
__global__ __launch_bounds__(256) void k_attn_gemm(const _Float16* __restrict__ Y1,
    const _Float16* __restrict__ r16, const _Float16* __restrict__ BattnT,
    const _Float16* __restrict__ WtT, float* __restrict__ tmp, float* __restrict__ rT, int t)
{
    __shared__ _Float16 sA[64*40];
    __shared__ _Float16 sB[64*40];
    const int tid = threadIdx.x;
    const int n0 = blockIdx.x*64, m0 = blockIdx.y*64, zz = blockIdx.z;
    const int lane = tid & 63, wv = tid >> 6;
    const int wm = (wv & 1)*32, wn = (wv >> 1)*32;
    const int q = lane >> 4, lm = lane & 15;
    const int am = tid >> 2, kg = (tid & 3)*8;
    const int row = m0 + am;
    const int nch = zz ? 8 : 16;
    const _Float16* aY = Y1 + ((size_t)row*L_ + t)*H_;
    const _Float16* aR = r16 + (size_t)row*H_;
    const _Float16* bRow = zz ? (WtT + (size_t)(n0 + am)*256) : (BattnT + (size_t)(n0 + am)*512);
    floatx4 acc00 = {0.f,0.f,0.f,0.f}, acc01 = acc00, acc10 = acc00, acc11 = acc00;
    for (int ch = 0; ch < nch; ++ch) {
        const int k0 = ch*32;
        half8 av;
        if (zz) av = *(const half8*)(aR + k0 + kg);
        else    av = (k0 < 256) ? *(const half8*)(aY + k0 + kg) : *(const half8*)(aR + (k0 - 256) + kg);
        half8 bv = *(const half8*)(bRow + k0 + kg);
        __syncthreads();
        *(half8*)(sA + am*40 + kg) = av;
        *(half8*)(sB + am*40 + kg) = bv;
        __syncthreads();
        half8 a0v = *(const half8*)(sA + (wm + lm)*40 + q*8);
        half8 a1v = *(const half8*)(sA + (wm + 16 + lm)*40 + q*8);
        half8 b0v = *(const half8*)(sB + (wn + lm)*40 + q*8);
        half8 b1v = *(const half8*)(sB + (wn + 16 + lm)*40 + q*8);
        acc00 = MFMA16(a0v, b0v, acc00); acc01 = MFMA16(a0v, b1v, acc01);
        acc10 = MFMA16(a1v, b0v, acc10); acc11 = MFMA16(a1v, b1v, acc11);
    }
    float* dst = zz ? rT : tmp;
    int rb = m0 + wm + q*4, col = n0 + wn + lm;
    #pragma unroll
    for (int r = 0; r < 4; ++r) {
        dst[(size_t)(rb + r)*H_ + col]           = acc00[r];
        dst[(size_t)(rb + r)*H_ + col + 16]      = acc01[r];
        dst[(size_t)(rb + 16 + r)*H_ + col]      = acc10[r];
        dst[(size_t)(rb + 16 + r)*H_ + col + 16] = acc11[r];
    }
}

// ---------------------------------------------------------------- attention score + r update
// grid 1024 (one block per combined row). Skips dead rows (t>=s_cap) and masked l (exact).
__global__ __launch_bounds__(256) void k_attn_score(
    const _Float16* __restrict__ WyY16, const _Float16* __restrict__ Y0,
    const float* __restrict__ tmp, const float* __restrict__ rT,
    const float* __restrict__ w_a,
    _Float16* __restrict__ r16, _Float16* __restrict__ rL16,
    const int* __restrict__ s1, const int* __restrict__ s2, int t)
{
    const int row = blockIdx.x;
    int sCap, sAtt;
    if (row < B_) { sCap = s2[row];       sAtt = s1[row]; }
    else          { sCap = s1[row - B_];  sAtt = s2[row - B_]; }
    if (t >= sCap) return;               // r for this row is never read again

    __shared__ float sTmp[256];
    __shared__ float sWa[256];
    __shared__ float sLog[64];
    __shared__ float sAl[64];
    const int tid = threadIdx.x;
    sTmp[tid] = tmp[row*256 + tid];
    sWa[tid]  = w_a[tid];
    __syncthreads();

    const int wv = tid >> 6, lane = tid & 63;
    for (int l = wv; l < sAtt; l += 4) {
        const _Float16* p = WyY16 + ((size_t)row*L_ + l)*H_ + lane*4;
        half4_t yv = *(const half4_t*)p;
        float v = 0.f;
        #pragma unroll
        for (int k = 0; k < 4; ++k) {
            int h = lane*4 + k;
            v += fast_tanh((float)yv[k] + sTmp[h]) * sWa[h];
        }
        #pragma unroll
        for (int off = 32; off > 0; off >>= 1) v += __shfl_down(v, off);
        if (lane == 0) sLog[l] = v;
    }
    __syncthreads();
    if (tid < 64) {
        float x = (tid < sAtt) ? sLog[tid] : -3.4e38f;
        float m = x;
        #pragma unroll
        for (int off = 32; off > 0; off >>= 1) m = fmaxf(m, __shfl_xor(m, off));
        float e = (tid < sAtt) ? __expf(x - m) : 0.f;
        float s = e;
        #pragma unroll
        for (int off = 32; off > 0; off >>= 1) s += __shfl_xor(s, off);
        sAl[tid] = e / s;
    }
    __syncthreads();
    float acc = 0.f;
    const _Float16* yb = Y0 + (size_t)row*L_*H_ + tid;
    for (int l = 0; l < sAtt; ++l) acc += sAl[l] * (float)yb[(size_t)l*H_];
    float val = acc + fast_tanh(rT[row*256 + tid]);
    r16[row*256 + tid] = (_Float16)val;
    if (t == sCap - 1) rL16[row*256 + tid] = (_Float16)val;
}

// ---------------------------------------------------------------- ff = [rL | h2] @ (Wp_a|Wxa)
// grid (4,16)
__global__ __launch_bounds__(256) void k_final_gemm(const _Float16* __restrict__ rL16,
    const _Float16* __restrict__ h2, const _Float16* __restrict__ WfinT, float* __restrict__ ff)
{
    __shared__ _Float16 sA[64*40];
    __shared__ _Float16 sB[64*40];
    const int tid = threadIdx.x;
    const int n0 = blockIdx.x*64, m0 = blockIdx.y*64;
    const int lane = tid & 63, wv = tid >> 6;
    const int wm = (wv & 1)*32, wn = (wv >> 1)*32;
    const int q = lane >> 4, lm = lane & 15;
    const int am = tid >> 2, kg = (tid & 3)*8;
    const int row = m0 + am;
    const _Float16* bRow = WfinT + (size_t)(n0 + am)*512;
    floatx4 acc00 = {0.f,0.f,0.f,0.f}, acc01 = acc00, acc10 = acc00, acc11 = acc00;
    for (int ch = 0; ch < 16; ++ch) {
        const int k0 = ch*32;
        half8 av = (k0 < 256) ? *(const half8*)(rL16 + (size_t)row*H_ + k0 + kg)
                              : *(const half8*)(h2   + (size_t)row*H_ + (k0 - 256) + kg);
        half8 bv = *(const half8*)(bRow + k0 + kg);
        __syncthreads();
        *(half8*)(sA + am*40 + kg) = av;
        *(half8*)(sB + am*40 + kg) = bv;
        __syncthreads();
        half8 a0v = *(const half8*)(sA + (wm + lm)*40 + q*8);
        half8 a1v = *(const half8*)(sA + (wm + 16 + lm)*40 + q*8);
        half8 b0v = *(const half8*)(sB + (wn + lm)*40 + q*8);
        half8 b1v = *(const half8*)(sB + (wn + 16 + lm)*40 + q*8);
        acc00 = MFMA16(a0v, b0v, acc00); acc01 = MFMA16(a0v, b1v, acc01);
        acc10 = MFMA16(a1v, b0v, acc10); acc11 = MFMA16(a1v, b1v, acc11);
    }
    int rb = m0 + wm + q*4, col = n0 + wn + lm;
    #pragma unroll
    for (int r = 0; r < 4; ++r) {
        ff[(size_t)(rb + r)*H_ + col]           = acc00[r];
        ff[(size_t)(rb + r)*H_ + col + 16]      = acc01[r];
        ff[(size_t)(rb + 16 + r)*H_ + col]      = acc10[r];
        ff[(size_t)(rb + 16 + r)*H_ + col + 16] = acc11[r];
    }
}

// out[b] = (tanh(ff[b]) + tanh(ff[b+512])) @ U + b_out     grid 32, 256 thr
__global__ __launch_bounds__(256) void k_final_out(const float* __restrict__ ff,
    const float* __restrict__ U, const float* __restrict__ b_out, float* __restrict__ out)
{
    __shared__ float sTh[16*256];
    __shared__ float sU[512];
    const int tid = threadIdx.x;
    const int b0 = blockIdx.x*16;
    sU[tid] = U[tid]; sU[256 + tid] = U[256 + tid];
    for (int idx = tid; idx < 16*256; idx += 256) {
        int r = idx >> 8, h = idx & 255;
        sTh[idx] = fast_tanh(ff[(size_t)(b0 + r)*256 + h]) + fast_tanh(ff[(size_t)(b0 + r + 512)*256 + h]);
    }
    __syncthreads();
    const int wv = tid >> 6, lane = tid & 63;
    for (int r = wv; r < 16; r += 4) {
        float p0 = 0.f, p1 = 0.f;
        #pragma unroll
        for (int k = 0; k < 4; ++k) {
            int h = lane*4 + k;
            float v = sTh[r*256 + h];
            p0 += v * sU[h*2];
            p1 += v * sU[h*2 + 1];
        }
        #pragma unroll
        for (int off = 32; off > 0; off >>= 1) { p0 += __shfl_down(p0, off); p1 += __shfl_down(p1, off); }
        if (lane == 0) {
            out[(b0 + r)*2]     = p0 + b_out[0];
            out[(b0 + r)*2 + 1] = p1 + b_out[1];
        }
    }
}

// ---------------------------------------------------------------- launcher
extern "C" void kernel_launch(void* const* d_in, const int* in_sizes, int n_in,
                              void* d_out, int out_size, void* d_ws, size_t ws_size,
                              hipStream_t stream)
{
    (void)in_sizes; (void)n_in; (void)out_size; (void)ws_size;
    const float* E    = (const float*)d_in[0];
    const float* Wx1  = (const float*)d_in[1];
    const float* Wh1  = (const float*)d_in[2];
    const float* b1   = (const float*)d_in[3];
    const float* Wx2  = (const float*)d_in[4];
    const float* Wh2  = (const float*)d_in[5];
    const float* b2   = (const float*)d_in[6];
    const float* W_y  = (const float*)d_in[7];
    const float* Wh_a = (const float*)d_in[8];
    const float* Wr_a = (const float*)d_in[9];
    const float* w_a  = (const float*)d_in[10];
    const float* Wt_a = (const float*)d_in[11];
    const float* Wp_a = (const float*)d_in[12];
    const float* Wxa  = (const float*)d_in[13];
    const float* U    = (const float*)d_in[14];
    const float* b_o  = (const float*)d_in[15];
    const int* in1 = (const int*)d_in[16];
    const int* in2 = (const int*)d_in[17];
    const int* s1  = (const int*)d_in[18];
    const int* s2  = (const int*)d_in[19];
    float* out = (float*)d_out;

    char* p = (char*)d_ws;
    auto alloc = [&](size_t bytes) { char* r = p; p += (bytes + 255) & ~(size_t)255; return r; };
    float*    c     = (float*)   alloc(2ull*BT*H_*4);        // 2 MB   (zero region start)
    _Float16* h16   = (_Float16*)alloc(4ull*BT*H_*2);        // 2 MB   [set][parity]
    _Float16* r16   = (_Float16*)alloc((size_t)BT*H_*2);     // 0.5 MB (zero region end)
    _Float16* X16   = (_Float16*)alloc((size_t)BT*L_*KX*2);  // 39.3 MB
    _Float16* Y16   = (_Float16*)alloc(2ull*BT*L_*H_*2);     // 62.9 MB
    _Float16* WyY16 = (_Float16*)alloc((size_t)BT*L_*H_*2);  // 31.5 MB
    _Float16* BcatT = (_Float16*)alloc(2ull*NG*KL*2);        // 2.36 MB
    _Float16* AW    = (_Float16*)alloc(393216ull*2);         // 0.79 MB
    float*    tmp   = (float*)   alloc((size_t)BT*H_*4);     // 1 MB
    float*    rT    = (float*)   alloc((size_t)BT*H_*4);     // 1 MB
    _Float16* rL16  = (_Float16*)alloc((size_t)BT*H_*2);     // 0.5 MB
    float*    ff    = (float*)   alloc((size_t)BT*H_*4);     // 1 MB

    _Float16* WyT    = AW;
    _Float16* BattnT = AW + 65536;
    _Float16* WtT    = AW + 196608;
    _Float16* WfinT  = AW + 262144;

    // zero c + h16 + r16 (contiguous: 4718592 B = 1179648 u32)
    k_zero<<<1152, 256, 0, stream>>>((uint32_t*)c, 1179648);
    k_gather<<<9600, 256, 0, stream>>>(E, in1, in2, X16);
    k_prep_lstmW<<<4608, 256, 0, stream>>>(Wx1, Wh1, Wx2, Wh2, BcatT);
    k_prep_attnW<<<1536, 256, 0, stream>>>(W_y, Wh_a, Wr_a, Wt_a, Wp_a, Wxa, AW);

    for (int t = 0; t < L_; ++t)
        k_lstm_step<<<dim3(16, 16, 2), 256, 0, stream>>>(X16, h16, c, Y16, BcatT, b1, b2, s1, s2, t);

    k_gemm_wyy<<<dim3(4, 960), 256, 0, stream>>>(Y16, WyT, WyY16);

    _Float16* Y1set = Y16 + (size_t)BT*L_*H_;                 // lstm2 outputs
    for (int t = 0; t < L_; ++t) {
        k_attn_gemm<<<dim3(4, 16, 2), 256, 0, stream>>>(Y1set, r16, BattnT, WtT, tmp, rT, t);
        k_attn_score<<<1024, 256, 0, stream>>>(WyY16, Y16, tmp, rT, w_a, r16, rL16, s1, s2, t);
    }

    _Float16* h2f = h16 + 2ull*BT*H_;                         // set1, parity 0 (after t=59)
    k_final_gemm<<<dim3(4, 16), 256, 0, stream>>>(rL16, h2f, WfinT, ff);
    k_final_out<<<32, 256, 0, stream>>>(ff, U, b_o, out);
}

// Round 2
// 2724.282 us; speedup vs baseline: 1.0165x; 1.0165x over previous
//
#include <hip/hip_runtime.h>
#include <cstdint>
#include <cstddef>

// Problem constants
#define B_  512
#define L_  60
#define D_  300
#define H_  256
#define BT  1024          // combined batch (2 branches)
#define KX  320           // D padded to multiple of 32 (300 -> 320, zeros in pad)
#define KL  576           // LSTM GEMM K: 320 (x) + 256 (h)
#define NG  1024          // 4*H gate width

typedef _Float16 half8  __attribute__((ext_vector_type(8)));
typedef _Float16 half4_t __attribute__((ext_vector_type(4)));
typedef float    floatx4 __attribute__((ext_vector_type(4)));

__device__ __forceinline__ float fast_tanh(float x){ float e = __expf(2.f*x); return 1.f - 2.f/(e + 1.f); }
__device__ __forceinline__ float sigm(float x){ return 1.f/(1.f + __expf(-x)); }

#define MFMA16(a,b,c) __builtin_amdgcn_mfma_f32_16x16x32_f16(a,b,c,0,0,0)

// ---------------------------------------------------------------- utility
__global__ void k_zero(uint32_t* __restrict__ p, int n){
    int i = blockIdx.x*blockDim.x + threadIdx.x;
    int st = gridDim.x*blockDim.x;
    for (; i < n; i += st) p[i] = 0u;
}

// Gather embeddings for [input1; input2] -> X16[1024][60][320] f16 (pad zeros)
__global__ __launch_bounds__(256) void k_gather(const float* __restrict__ E,
    const int* __restrict__ in1, const int* __restrict__ in2, _Float16* __restrict__ X16)
{
    int gid = blockIdx.x*256 + threadIdx.x;
    int row = gid / (L_*40);
    int rem = gid - row*(L_*40);
    int t  = rem / 40;
    int ch = rem - t*40;
    int k0 = ch*8;
    int tok = (row < B_) ? in1[row*L_ + t] : in2[(row - B_)*L_ + t];
    const float* src = E + (size_t)tok*D_ + k0;
    half8 out;
    #pragma unroll
    for (int k = 0; k < 8; ++k) out[k] = (_Float16)0.f;
    if (k0 + 8 <= D_) {
        float4 a = *(const float4*)(src);
        float4 b = *(const float4*)(src + 4);
        out[0]=(_Float16)a.x; out[1]=(_Float16)a.y; out[2]=(_Float16)a.z; out[3]=(_Float16)a.w;
        out[4]=(_Float16)b.x; out[5]=(_Float16)b.y; out[6]=(_Float16)b.z; out[7]=(_Float16)b.w;
    } else if (k0 < D_) {
        float4 a = *(const float4*)(src);
        out[0]=(_Float16)a.x; out[1]=(_Float16)a.y; out[2]=(_Float16)a.z; out[3]=(_Float16)a.w;
    }
    *(half8*)(X16 + ((size_t)row*L_ + t)*KX + k0) = out;
}

// LSTM weights -> BcatT[set][n=1024][k=576] f16; k<300 Wx, 300..319 zero, >=320 Wh
__global__ __launch_bounds__(256) void k_prep_lstmW(const float* __restrict__ Wx1, const float* __restrict__ Wh1,
    const float* __restrict__ Wx2, const float* __restrict__ Wh2, _Float16* __restrict__ BcatT)
{
    int idx = blockIdx.x*256 + threadIdx.x;
    int set = (idx >= KL*NG) ? 1 : 0;
    int rem = idx - set*(KL*NG);
    int k = rem >> 10, n = rem & 1023;
    const float* Wx = set ? Wx2 : Wx1;
    const float* Wh = set ? Wh2 : Wh1;
    float v = 0.f;
    if (k < D_)       v = Wx[k*NG + n];
    else if (k >= KX) v = Wh[(k - KX)*NG + n];
    BcatT[((size_t)set*NG + n)*KL + k] = (_Float16)v;
}

// Attention weights f16, transposed [n][k].
// AW layout (elem offsets): WyT@0 [256][256]
//   BcombT@65536 [n=512][k=512]: n<256: (k<256?Wh_a:Wr_a) col n; n>=256: (k<256?0:Wt_a) col n-256
//   WfinT@327680 [n=256][k=512]: (k<256?Wp_a:Wxa) col n
// grid 1792 blocks
__global__ __launch_bounds__(256) void k_prep_attnW(const float* __restrict__ W_y,
    const float* __restrict__ Wh_a, const float* __restrict__ Wr_a, const float* __restrict__ Wt_a,
    const float* __restrict__ Wp_a, const float* __restrict__ Wxa, _Float16* __restrict__ AW)
{
    int idx = blockIdx.x*256 + threadIdx.x;
    float v; int dst;
    if (idx < 65536) {
        int k = idx >> 8, n = idx & 255;
        v = W_y[k*256 + n];
        dst = n*256 + k;
    } else if (idx < 327680) {
        int j = idx - 65536;
        int n = j >> 9, k = j & 511;
        if (n < 256) v = (k < 256) ? Wh_a[k*256 + n] : Wr_a[(k - 256)*256 + n];
        else         v = (k < 256) ? 0.f : Wt_a[(k - 256)*256 + (n - 256)];
        dst = 65536 + j;
    } else {
        int j = idx - 327680;
        int n = j >> 9, k = j & 511;
        v = (k < 256) ? Wp_a[k*256 + n] : Wxa[(k - 256)*256 + n];
        dst = 327680 + j;
    }
    AW[dst] = (_Float16)v;
}

// ---------------------------------------------------------------- fused LSTM step
// 64x128 tile, grid (ht=8, mt=32), 256 thr (4 waves, each 64x32).
// Software-prefetched staging; sG unions with sA/sB.
__global__ __launch_bounds__(256) void k_lstm_step(
    const _Float16* __restrict__ X16, _Float16* __restrict__ h16,
    float* __restrict__ c, _Float16* __restrict__ Y16,
    const _Float16* __restrict__ BcatT,
    const float* __restrict__ b1, const float* __restrict__ b2,
    const int* __restrict__ s1, const int* __restrict__ s2, int t)
{
    __shared__ float sG[64*129];                 // 33 KB; also holds sA/sB during GEMM
    _Float16* sA = (_Float16*)sG;                // 64 rows * 40
    _Float16* sB = sA + 64*40;                   // 128 cols * 40

    const int tid = threadIdx.x;
    const int ht = blockIdx.x, mt = blockIdx.y;
    const int set = mt >> 4;
    const int m0 = mt*64;
    const int lane = tid & 63, wv = tid >> 6;
    const int wn = wv*32;
    const int q = lane >> 4, lm = lane & 15;
    const int p_in = t & 1, p_out = (t + 1) & 1;
    const _Float16* hin  = h16 + ((size_t)(set*2 + p_in))*BT*H_;
    _Float16*       hout = h16 + ((size_t)(set*2 + p_out))*BT*H_;

    // A staging: 64 rows, 4 thr/row, 8 halves each
    const int amA = tid >> 2, kgA = (tid & 3)*8;
    const int grA = m0 + amA;
    const int ris = grA & 1023;                  // row in set
    const int xrow = set ? ((ris + 512) & 1023) : ris;
    const _Float16* aX = X16 + ((size_t)xrow*L_ + t)*KX;
    const _Float16* aH = hin + (size_t)ris*H_;
    // B staging: 128 cols, 2 thr/col, 16 halves each
    const int colT = tid >> 1, segB = (tid & 1)*16;
    const int gn = ((colT >> 5) << 8) + ht*32 + (colT & 31);   // gate-strided col
    const _Float16* bRow = BcatT + ((size_t)set*NG + gn)*KL;

    floatx4 acc[4][2];
    #pragma unroll
    for (int mi = 0; mi < 4; ++mi)
        #pragma unroll
        for (int ni = 0; ni < 2; ++ni) acc[mi][ni] = (floatx4){0.f,0.f,0.f,0.f};

    auto loadA = [&](int ch) -> half8 {
        int kk = ch*32 + kgA;
        return (kk < KX) ? *(const half8*)(aX + kk) : *(const half8*)(aH + (kk - KX));
    };

    half8 av  = loadA(0);
    half8 bv0 = *(const half8*)(bRow + segB);
    half8 bv1 = *(const half8*)(bRow + segB + 8);

    for (int ch = 0; ch < 18; ++ch) {
        __syncthreads();
        *(half8*)(sA + amA*40 + kgA)     = av;
        *(half8*)(sB + colT*40 + segB)   = bv0;
        *(half8*)(sB + colT*40 + segB+8) = bv1;
        __syncthreads();
        if (ch < 17) {
            av  = loadA(ch + 1);
            bv0 = *(const half8*)(bRow + (ch+1)*32 + segB);
            bv1 = *(const half8*)(bRow + (ch+1)*32 + segB + 8);
        }
        half8 af[4], bf[2];
        #pragma unroll
        for (int mi = 0; mi < 4; ++mi) af[mi] = *(const half8*)(sA + (mi*16 + lm)*40 + q*8);
        #pragma unroll
        for (int ni = 0; ni < 2; ++ni) bf[ni] = *(const half8*)(sB + (wn + ni*16 + lm)*40 + q*8);
        #pragma unroll
        for (int mi = 0; mi < 4; ++mi)
            #pragma unroll
            for (int ni = 0; ni < 2; ++ni) acc[mi][ni] = MFMA16(af[mi], bf[ni], acc[mi][ni]);
    }

    __syncthreads();   // done reading sA/sB; safe to overwrite as sG
    #pragma unroll
    for (int mi = 0; mi < 4; ++mi)
        #pragma unroll
        for (int ni = 0; ni < 2; ++ni)
            #pragma unroll
            for (int r = 0; r < 4; ++r)
                sG[(mi*16 + q*4 + r)*129 + (wn + ni*16 + lm)] = acc[mi][ni][r];
    __syncthreads();

    const float* bias = set ? b2 : b1;
    for (int idx = tid; idx < 2048; idx += 256) {
        int row = idx & 63, hl = idx >> 6;       // hl 0..31
        int gr = m0 + row;
        int rs = gr & 1023;
        int h = ht*32 + hl;
        float gi = sG[row*129 + hl];
        float gj = sG[row*129 + 32 + hl];
        float gf = sG[row*129 + 64 + hl];
        float go = sG[row*129 + 96 + hl];
        gi += bias[h]; gj += bias[256 + h]; gf += bias[512 + h]; go += bias[768 + h];
        int sl = (set == 0) ? ((rs < B_) ? s1[rs] : s2[rs - B_])
                            : ((rs < B_) ? s2[rs] : s1[rs - B_]);
        size_t ci = (size_t)gr*H_ + h;
        float c_old = c[ci];
        float c_new = c_old*sigm(gf + 1.f) + sigm(gi)*fast_tanh(gj);
        float h_new = fast_tanh(c_new)*sigm(go);
        bool act = (t < sl);
        float h_old = (float)hin[(size_t)rs*H_ + h];
        c[ci] = act ? c_new : c_old;
        hout[(size_t)rs*H_ + h] = (_Float16)(act ? h_new : h_old);
        Y16[((size_t)gr*L_ + t)*H_ + h] = act ? (_Float16)h_new : (_Float16)0.f;
    }
}

// ---------------------------------------------------------------- WyY = Y(set0) @ W_y
// grid (nt=4, mt=960): M=61440, N=256, K=256, f16 out
__global__ __launch_bounds__(256) void k_gemm_wyy(const _Float16* __restrict__ Y0,
    const _Float16* __restrict__ WyT, _Float16* __restrict__ WyY16)
{
    __shared__ _Float16 sA[64*40];
    __shared__ _Float16 sB[64*40];
    const int tid = threadIdx.x;
    const int n0 = blockIdx.x*64, m0 = blockIdx.y*64;
    const int lane = tid & 63, wv = tid >> 6;
    const int wm = (wv & 1)*32, wn = (wv >> 1)*32;
    const int q = lane >> 4, lm = lane & 15;
    const int am = tid >> 2, kg = (tid & 3)*8;
    const _Float16* aRow = Y0  + (size_t)(m0 + am)*H_;
    const _Float16* bRow = WyT + (size_t)(n0 + am)*H_;
    floatx4 acc00 = {0.f,0.f,0.f,0.f}, acc01 = acc00, acc10 = acc00, acc11 = acc00;
    half8 av = *(const half8*)(aRow + kg);
    half8 bv = *(const half8*)(bRow + kg);
    for (int ch = 0; ch < 8; ++ch) {
        __syncthreads();
        *(half8*)(sA + am*40 + kg) = av;
        *(half8*)(sB + am*40 + kg) = bv;
        __syncthreads();
        if (ch < 7) {
            av = *(const half8*)(aRow + (ch+1)*32 + kg);
            bv = *(const half8*)(bRow + (ch+1)*32 + kg);
        }
        half8 a0v = *(const half8*)(sA + (wm + lm)*40 + q*8);
        half8 a1v = *(const half8*)(sA + (wm + 16 + lm)*40 + q*8);
        half8 b0v = *(const half8*)(sB + (wn + lm)*40 + q*8);
        half8 b1v = *(const half8*)(sB + (wn + 16 + lm)*40 + q*8);
        acc00 = MFMA16(a0v, b0v, acc00); acc01 = MFMA16(a0v, b1v, acc01);
        acc10 = MFMA16(a1v, b0v, acc10); acc11 = MFMA16(a1v, b1v, acc11);
    }
    int rb = m0 + wm + q*4, col = n0 + wn + lm;
    #pragma unroll
    for (int r = 0; r < 4; ++r) {
        WyY16[(size_t)(rb + r)*H_ + col]           = (_Float16)acc00[r];
        WyY16[(size_t)(rb + r)*H_ + col + 16]      = (_Float16)acc01[r];
        WyY16[(size_t)(rb + 16 + r)*H_ + col]      = (_Float16)acc10[r];
        WyY16[(size_t)(rb + 16 + r)*H_ + col + 16] = (_Float16)acc11[r];
    }
}

// ---------------------------------------------------------------- attention per-step GEMM
// rW = [Y2_t | r] @ BcombT : M=1024, N=512, K=512. rW[:,0:256]=tmp, rW[:,256:512]=r@Wt_a
// grid (nt=8, mt=16)
__global__ __launch_bounds__(256) void k_attn_gemm(const _Float16* __restrict__ Y1,
    const _Float16* __restrict__ r16, const _Float16* __restrict__ BcombT,
    float* __restrict__ rW, int t)
{
    __shared__ _Float16 sA[64*40];
    __shared__ _Float16 sB[64*40];
    const int tid = threadIdx.x;
    const int n0 = blockIdx.x*64, m0 = blockIdx.y*64;
    const int lane = tid & 63, wv = tid >> 6;
    const int wm = (wv & 1)*32, wn = (wv >> 1)*32;
    const int q = lane >> 4, lm = lane & 15;
    const int am = tid >> 2, kg = (tid & 3)*8;
    const int row = m0 + am;
    const _Float16* aY = Y1 + ((size_t)row*L_ + t)*H_;
    const _Float16* aR = r16 + (size_t)row*H_;
    const _Float16* bRow = BcombT + (size_t)(n0 + am)*512;
    floatx4 acc00 = {0.f,0.f,0.f,0.f}, acc01 = acc00, acc10 = acc00, acc11 = acc00;
    auto loadA = [&](int ch) -> half8 {
        int kk = ch*32 + kg;
        return (kk < 256) ? *(const half8*)(aY + kk) : *(const half8*)(aR + (kk - 256));
    };
    half8 av = loadA(0);
    half8 bv = *(const half8*)(bRow + kg);
    for (int ch = 0; ch < 16; ++ch) {
        __syncthreads();
        *(half8*)(sA + am*40 + kg) = av;
        *(half8*)(sB + am*40 + kg) = bv;
        __syncthreads();
        if (ch < 15) {
            av = loadA(ch + 1);
            bv = *(const half8*)(bRow + (ch+1)*32 + kg);
        }
        half8 a0v = *(const half8*)(sA + (wm + lm)*40 + q*8);
        half8 a1v = *(const half8*)(sA + (wm + 16 + lm)*40 + q*8);
        half8 b0v = *(const half8*)(sB + (wn + lm)*40 + q*8);
        half8 b1v = *(const half8*)(sB + (wn + 16 + lm)*40 + q*8);
        acc00 = MFMA16(a0v, b0v, acc00); acc01 = MFMA16(a0v, b1v, acc01);
        acc10 = MFMA16(a1v, b0v, acc10); acc11 = MFMA16(a1v, b1v, acc11);
    }
    int rb = m0 + wm + q*4, col = n0 + wn + lm;
    #pragma unroll
    for (int r = 0; r < 4; ++r) {
        rW[(size_t)(rb + r)*512 + col]           = acc00[r];
        rW[(size_t)(rb + r)*512 + col + 16]      = acc01[r];
        rW[(size_t)(rb + 16 + r)*512 + col]      = acc10[r];
        rW[(size_t)(rb + 16 + r)*512 + col + 16] = acc11[r];
    }
}

// ---------------------------------------------------------------- attention score + r update
// grid 1024 (one block per combined row). Skips dead rows (t>=s_cap) and masked l (exact).
__global__ __launch_bounds__(256) void k_attn_score(
    const _Float16* __restrict__ WyY16, const _Float16* __restrict__ Y0,
    const float* __restrict__ rW, const float* __restrict__ w_a,
    _Float16* __restrict__ r16, _Float16* __restrict__ rL16,
    const int* __restrict__ s1, const int* __restrict__ s2, int t)
{
    const int row = blockIdx.x;
    int sCap, sAtt;
    if (row < B_) { sCap = s2[row];       sAtt = s1[row]; }
    else          { sCap = s1[row - B_];  sAtt = s2[row - B_]; }
    if (t >= sCap) return;               // r for this row is never read again

    __shared__ float sTmp[256];
    __shared__ float sWa[256];
    __shared__ float sLog[64];
    __shared__ float sAl[64];
    const int tid = threadIdx.x;
    sTmp[tid] = rW[row*512 + tid];
    sWa[tid]  = w_a[tid];
    __syncthreads();

    const int wv = tid >> 6, lane = tid & 63;
    for (int l = wv; l < sAtt; l += 4) {
        const _Float16* p = WyY16 + ((size_t)row*L_ + l)*H_ + lane*4;
        half4_t yv = *(const half4_t*)p;
        float v = 0.f;
        #pragma unroll
        for (int k = 0; k < 4; ++k) {
            int h = lane*4 + k;
            v += fast_tanh((float)yv[k] + sTmp[h]) * sWa[h];
        }
        #pragma unroll
        for (int off = 32; off > 0; off >>= 1) v += __shfl_down(v, off);
        if (lane == 0) sLog[l] = v;
    }
    __syncthreads();
    if (tid < 64) {
        float x = (tid < sAtt) ? sLog[tid] : -3.4e38f;
        float m = x;
        #pragma unroll
        for (int off = 32; off > 0; off >>= 1) m = fmaxf(m, __shfl_xor(m, off));
        float e = (tid < sAtt) ? __expf(x - m) : 0.f;
        float s = e;
        #pragma unroll
        for (int off = 32; off > 0; off >>= 1) s += __shfl_xor(s, off);
        sAl[tid] = e / s;
    }
    __syncthreads();
    float acc = 0.f;
    const _Float16* yb = Y0 + (size_t)row*L_*H_ + tid;
    for (int l = 0; l < sAtt; ++l) acc += sAl[l] * (float)yb[(size_t)l*H_];
    float val = acc + fast_tanh(rW[row*512 + 256 + tid]);
    r16[row*256 + tid] = (_Float16)val;
    if (t == sCap - 1) rL16[row*256 + tid] = (_Float16)val;
}

// ---------------------------------------------------------------- ff = [rL | h2] @ (Wp_a|Wxa)
// grid (4,16)
__global__ __launch_bounds__(256) void k_final_gemm(const _Float16* __restrict__ rL16,
    const _Float16* __restrict__ h2, const _Float16* __restrict__ WfinT, float* __restrict__ ff)
{
    __shared__ _Float16 sA[64*40];
    __shared__ _Float16 sB[64*40];
    const int tid = threadIdx.x;
    const int n0 = blockIdx.x*64, m0 = blockIdx.y*64;
    const int lane = tid & 63, wv = tid >> 6;
    const int wm = (wv & 1)*32, wn = (wv >> 1)*32;
    const int q = lane >> 4, lm = lane & 15;
    const int am = tid >> 2, kg = (tid & 3)*8;
    const int row = m0 + am;
    const _Float16* bRow = WfinT + (size_t)(n0 + am)*512;
    floatx4 acc00 = {0.f,0.f,0.f,0.f}, acc01 = acc00, acc10 = acc00, acc11 = acc00;
    for (int ch = 0; ch < 16; ++ch) {
        const int k0 = ch*32;
        half8 av = (k0 < 256) ? *(const half8*)(rL16 + (size_t)row*H_ + k0 + kg)
                              : *(const half8*)(h2   + (size_t)row*H_ + (k0 - 256) + kg);
        half8 bv = *(const half8*)(bRow + k0 + kg);
        __syncthreads();
        *(half8*)(sA + am*40 + kg) = av;
        *(half8*)(sB + am*40 + kg) = bv;
        __syncthreads();
        half8 a0v = *(const half8*)(sA + (wm + lm)*40 + q*8);
        half8 a1v = *(const half8*)(sA + (wm + 16 + lm)*40 + q*8);
        half8 b0v = *(const half8*)(sB + (wn + lm)*40 + q*8);
        half8 b1v = *(const half8*)(sB + (wn + 16 + lm)*40 + q*8);
        acc00 = MFMA16(a0v, b0v, acc00); acc01 = MFMA16(a0v, b1v, acc01);
        acc10 = MFMA16(a1v, b0v, acc10); acc11 = MFMA16(a1v, b1v, acc11);
    }
    int rb = m0 + wm + q*4, col = n0 + wn + lm;
    #pragma unroll
    for (int r = 0; r < 4; ++r) {
        ff[(size_t)(rb + r)*H_ + col]           = acc00[r];
        ff[(size_t)(rb + r)*H_ + col + 16]      = acc01[r];
        ff[(size_t)(rb + 16 + r)*H_ + col]      = acc10[r];
        ff[(size_t)(rb + 16 + r)*H_ + col + 16] = acc11[r];
    }
}

// out[b] = (tanh(ff[b]) + tanh(ff[b+512])) @ U + b_out     grid 32, 256 thr
__global__ __launch_bounds__(256) void k_final_out(const float* __restrict__ ff,
    const float* __restrict__ U, const float* __restrict__ b_out, float* __restrict__ out)
{
    __shared__ float sTh[16*256];
    __shared__ float sU[512];
    const int tid = threadIdx.x;
    const int b0 = blockIdx.x*16;
    sU[tid] = U[tid]; sU[256 + tid] = U[256 + tid];
    for (int idx = tid; idx < 16*256; idx += 256) {
        int r = idx >> 8, h = idx & 255;
        sTh[idx] = fast_tanh(ff[(size_t)(b0 + r)*256 + h]) + fast_tanh(ff[(size_t)(b0 + r + 512)*256 + h]);
    }
    __syncthreads();
    const int wv = tid >> 6, lane = tid & 63;
    for (int r = wv; r < 16; r += 4) {
        float p0 = 0.f, p1 = 0.f;
        #pragma unroll
        for (int k = 0; k < 4; ++k) {
            int h = lane*4 + k;
            float v = sTh[r*256 + h];
            p0 += v * sU[h*2];
            p1 += v * sU[h*2 + 1];
        }
        #pragma unroll
        for (int off = 32; off > 0; off >>= 1) { p0 += __shfl_down(p0, off); p1 += __shfl_down(p1, off); }
        if (lane == 0) {
            out[(b0 + r)*2]     = p0 + b_out[0];
            out[(b0 + r)*2 + 1] = p1 + b_out[1];
        }
    }
}

// ---------------------------------------------------------------- launcher
extern "C" void kernel_launch(void* const* d_in, const int* in_sizes, int n_in,
                              void* d_out, int out_size, void* d_ws, size_t ws_size,
                              hipStream_t stream)
{
    (void)in_sizes; (void)n_in; (void)out_size; (void)ws_size;
    const float* E    = (const float*)d_in[0];
    const float* Wx1  = (const float*)d_in[1];
    const float* Wh1  = (const float*)d_in[2];
    const float* b1   = (const float*)d_in[3];
    const float* Wx2  = (const float*)d_in[4];
    const float* Wh2  = (const float*)d_in[5];
    const float* b2   = (const float*)d_in[6];
    const float* W_y  = (const float*)d_in[7];
    const float* Wh_a = (const float*)d_in[8];
    const float* Wr_a = (const float*)d_in[9];
    const float* w_a  = (const float*)d_in[10];
    const float* Wt_a = (const float*)d_in[11];
    const float* Wp_a = (const float*)d_in[12];
    const float* Wxa  = (const float*)d_in[13];
    const float* U    = (const float*)d_in[14];
    const float* b_o  = (const float*)d_in[15];
    const int* in1 = (const int*)d_in[16];
    const int* in2 = (const int*)d_in[17];
    const int* s1  = (const int*)d_in[18];
    const int* s2  = (const int*)d_in[19];
    float* out = (float*)d_out;

    char* p = (char*)d_ws;
    auto alloc = [&](size_t bytes) { char* r = p; p += (bytes + 255) & ~(size_t)255; return r; };
    float*    c     = (float*)   alloc(2ull*BT*H_*4);        // zero region start
    _Float16* h16   = (_Float16*)alloc(4ull*BT*H_*2);        // [set][parity]
    _Float16* r16   = (_Float16*)alloc((size_t)BT*H_*2);     // zero region end
    _Float16* X16   = (_Float16*)alloc((size_t)BT*L_*KX*2);
    _Float16* Y16   = (_Float16*)alloc(2ull*BT*L_*H_*2);
    _Float16* WyY16 = (_Float16*)alloc((size_t)BT*L_*H_*2);
    _Float16* BcatT = (_Float16*)alloc(2ull*NG*KL*2);
    _Float16* AW    = (_Float16*)alloc(458752ull*2);
    float*    rW    = (float*)   alloc((size_t)BT*512*4);
    _Float16* rL16  = (_Float16*)alloc((size_t)BT*H_*2);
    float*    ff    = (float*)   alloc((size_t)BT*H_*4);

    _Float16* WyT    = AW;
    _Float16* BcombT = AW + 65536;
    _Float16* WfinT  = AW + 327680;

    // zero c + h16 + r16 (contiguous: 4718592 B = 1179648 u32)
    k_zero<<<1152, 256, 0, stream>>>((uint32_t*)c, 1179648);
    k_gather<<<9600, 256, 0, stream>>>(E, in1, in2, X16);
    k_prep_lstmW<<<4608, 256, 0, stream>>>(Wx1, Wh1, Wx2, Wh2, BcatT);
    k_prep_attnW<<<1792, 256, 0, stream>>>(W_y, Wh_a, Wr_a, Wt_a, Wp_a, Wxa, AW);

    for (int t = 0; t < L_; ++t)
        k_lstm_step<<<dim3(8, 32), 256, 0, stream>>>(X16, h16, c, Y16, BcatT, b1, b2, s1, s2, t);

    k_gemm_wyy<<<dim3(4, 960), 256, 0, stream>>>(Y16, WyT, WyY16);

    _Float16* Y1set = Y16 + (size_t)BT*L_*H_;                 // lstm2 outputs
    for (int t = 0; t < L_; ++t) {
        k_attn_gemm<<<dim3(8, 16), 256, 0, stream>>>(Y1set, r16, BcombT, rW, t);
        k_attn_score<<<1024, 256, 0, stream>>>(WyY16, Y16, rW, w_a, r16, rL16, s1, s2, t);
    }

    _Float16* h2f = h16 + 2ull*BT*H_;                         // set1, parity 0 (after t=59)
    k_final_gemm<<<dim3(4, 16), 256, 0, stream>>>(rL16, h2f, WfinT, ff);
    k_final_out<<<32, 256, 0, stream>>>(ff, U, b_o, out);
}